// Round 10
// baseline (101.103 us; speedup 1.0000x reference)
//
#include <hip/hip_runtime.h>

// VQEmbedding: B=32,T=1024,D=256,K=1024. N=32768 rows.
// Exact score (proven r2-r9): s = fl32( fl32(csqr_k + xsqr_i) - 2*dot_ik ), argmin,
// first-index ties via packed u64 keys. bf16 MFMA approx (fragment layout verified
// r4-r9); two-pass margin filter (M=1.5e-3); exact fp32 rescore (r2 chain).
// r10 change (r9 counters: LDS pipe ~51us/CU was the limit; MFMA only 17us):
//  - wave holds A-frags for ALL 64 block rows (afr[4][8], 128 VGPR) and covers only
//    16 nt (256 codes) -> 4 MFMAs per B-fragment ds_read (4x LDS-read reuse).
//  - staging via __builtin_amdgcn_global_load_lds width=16 (linear per-slot layout,
//    wave-uniform dst; kills pf registers + ds_write instructions).
//  - cross-wave per-row min combine through LDS (r6-proven) at pass boundary.

#define NROWS  32768
#define DDIM   256
#define KCODES 1024
#define MARGIN 1.5e-3f
#define CAP    1024
#define RPB    64          // rows per block = rows per wave (4 A-tiles of 16)
#define NCHUNK 16          // chunks per pass; chunk = 4 nt (1 per wave) = 32KB

typedef __attribute__((ext_vector_type(8))) short short8;
typedef __attribute__((ext_vector_type(4))) float f32x4;

__device__ __forceinline__ unsigned short f2bf(float f) {   // RNE f32->bf16
    unsigned u = __float_as_uint(f);
    return (unsigned short)((u + 0x7FFFu + ((u >> 16) & 1u)) >> 16);
}

// exact fp32 dot — BIT-IDENTICAL chain to r2-r9 (proven). DO NOT reorder.
__device__ __forceinline__ float exact_dot(const float* __restrict__ xrow,
                                           const float* __restrict__ crow) {
    const float4* xp = (const float4*)xrow;
    const float4* cp = (const float4*)crow;
    float A = 0.f, B = 0.f;
    #pragma unroll 8
    for (int d4 = 0; d4 < 32; ++d4) {
        float4 xv = xp[d4], cv = cp[d4];
        A = __fmaf_rn(xv.x, cv.x, A);
        A = __fmaf_rn(xv.y, cv.y, A);
        A = __fmaf_rn(xv.z, cv.z, A);
        A = __fmaf_rn(xv.w, cv.w, A);
    }
    #pragma unroll 8
    for (int d4 = 32; d4 < 64; ++d4) {
        float4 xv = xp[d4], cv = cp[d4];
        B = __fmaf_rn(xv.x, cv.x, B);
        B = __fmaf_rn(xv.y, cv.y, B);
        B = __fmaf_rn(xv.z, cv.z, B);
        B = __fmaf_rn(xv.w, cv.w, B);
    }
    return __fadd_rn(A, B);
}

// --- csqr[k] (proven r2-r9, unchanged) ---
__global__ __launch_bounds__(256) void vq_csqr(const float* __restrict__ cb,
                                               float* __restrict__ csqr) {
    int gid  = blockIdx.x * 256 + threadIdx.x;
    int w    = gid >> 6;
    int lane = threadIdx.x & 63;
    if (w >= KCODES) return;
    float4 v = reinterpret_cast<const float4*>(cb)[w * (DDIM / 4) + lane];
    float s = v.x * v.x + v.y * v.y + v.z * v.z + v.w * v.w;
    #pragma unroll
    for (int off = 32; off > 0; off >>= 1) s += __shfl_down(s, off, 64);
    if (lane == 0) csqr[w] = s;
}

// --- xsqr[r] (proven r3-r9, unchanged) ---
__global__ __launch_bounds__(256) void vq_xsqr(const float* __restrict__ x,
                                               float* __restrict__ xsqr) {
    int w = threadIdx.x >> 6, lane = threadIdx.x & 63;
    int row = blockIdx.x * 4 + w;
    float4 v = reinterpret_cast<const float4*>(x + (size_t)row * DDIM)[lane];
    float s = v.x * v.x + v.y * v.y + v.z * v.z + v.w * v.w;
    #pragma unroll
    for (int off = 32; off > 0; off >>= 1) s += __shfl_down(s, off, 64);
    if (lane == 0) xsqr[row] = s;
}

// --- cb -> bf16 B-fragments (layout verified r4-r9): frag(nt,ks): lane l elem i =
//     cb[nt*16 + (l&15)][ks*32 + (l>>4)*8 + i]; linear id = (nt*8+ks)*64 + l ---
__global__ __launch_bounds__(256) void vq_cbfrag(const float* __restrict__ cb,
                                                 short* __restrict__ cbh) {
    int id   = blockIdx.x * 256 + threadIdx.x;
    int lane = id & 63;
    int ks   = (id >> 6) & 7;
    int nt   = id >> 9;
    int code = nt * 16 + (lane & 15);
    int d0   = ks * 32 + (lane >> 4) * 8;
    const float4* p = (const float4*)(cb + (size_t)code * DDIM + d0);
    float4 a = p[0], b = p[1];
    short8 v;
    v[0] = (short)f2bf(a.x); v[1] = (short)f2bf(a.y);
    v[2] = (short)f2bf(a.z); v[3] = (short)f2bf(a.w);
    v[4] = (short)f2bf(b.x); v[5] = (short)f2bf(b.y);
    v[6] = (short)f2bf(b.z); v[7] = (short)f2bf(b.w);
    *(short8*)(cbh + (size_t)id * 8) = v;
}

// --- main: 64 rows/block; wave w covers codes w*256..+256; afr[4][8] in regs ---
__global__ __launch_bounds__(256, 2) void vq_main(const float* __restrict__ x,
                                                  const float* __restrict__ cb,
                                                  const short* __restrict__ cbh,
                                                  const float* __restrict__ csqr,
                                                  const float* __restrict__ xsqr,
                                                  float* __restrict__ out) {
    __shared__ short              bstage[2][4 * 8 * 64 * 8];  // 2 x 32KB (4 slots x 8KB)
    __shared__ float              csl[KCODES];                // 4KB
    __shared__ float              wred[4][RPB];               // per-wave row mins
    __shared__ float              thrl[RPB];
    __shared__ unsigned long long keys[RPB];
    __shared__ unsigned           list[CAP];
    __shared__ int                fidx[RPB];
    __shared__ int                cnt, ovf;

    const int t    = threadIdx.x;
    const int lane = t & 63;
    const int w    = t >> 6;         // 0..3 (wave = code quarter)
    const int r0   = blockIdx.x * RPB;
    const int lr   = lane & 15;
    const int lg   = lane >> 4;

    ((float4*)csl)[t] = ((const float4*)csqr)[t];
    if (t < RPB) keys[t] = ~0ULL;
    if (t == 0) { cnt = 0; ovf = 0; }

    // A-fragments for ALL 64 rows (4 tiles of 16). Mapping identical to r4-r9.
    short8 afr[4][8];
    #pragma unroll
    for (int tile = 0; tile < 4; ++tile) {
        const float* xr = x + (size_t)(r0 + tile * 16 + lr) * DDIM;
        #pragma unroll
        for (int ks = 0; ks < 8; ++ks) {
            float4 a = *(const float4*)&xr[ks * 32 + lg * 8];
            float4 b = *(const float4*)&xr[ks * 32 + lg * 8 + 4];
            short8 v;
            v[0] = (short)f2bf(a.x); v[1] = (short)f2bf(a.y);
            v[2] = (short)f2bf(a.z); v[3] = (short)f2bf(a.w);
            v[4] = (short)f2bf(b.x); v[5] = (short)f2bf(b.y);
            v[6] = (short)f2bf(b.z); v[7] = (short)f2bf(b.w);
            afr[tile][ks] = v;
        }
    }

    // DMA stage: wave w copies its nt = w*16 + c (8KB, linear) into slot w of buf.
    // global_load_lds: per-lane global src, wave-uniform LDS dst (+lane*16 in HW).
    const char* cbb = (const char*)cbh;
    auto stage_chunk = [&](int buf, int c) {
        const char* srcb = cbb + ((size_t)(w * 16 + c) << 13);      // nt * 8192
        char*       dstb = (char*)bstage[buf] + ((size_t)w << 13);  // slot w
        #pragma unroll
        for (int i = 0; i < 8; ++i) {
            const void* src = srcb + i * 1024 + lane * 16;
            __builtin_amdgcn_global_load_lds(
                (const __attribute__((address_space(1))) void*)src,
                (__attribute__((address_space(3))) void*)(dstb + i * 1024),
                16, 0, 0);
        }
    };

    stage_chunk(0, 0);
    __syncthreads();   // compiler drains vmcnt before barrier -> chunk 0 ready

    float runp[4][4];
    #pragma unroll
    for (int tile = 0; tile < 4; ++tile)
        #pragma unroll
        for (int j = 0; j < 4; ++j) runp[tile][j] = __builtin_inff();
    float thr[4][4];

    for (int cc = 0; cc < 2 * NCHUNK; ++cc) {
        const int c = cc & (NCHUNK - 1);
        if (cc + 1 < 2 * NCHUNK) stage_chunk((cc + 1) & 1, (cc + 1) & (NCHUNK - 1));

        // compute my slot's nt from buf[cc&1]
        const short* bs = bstage[cc & 1];
        short8 bv[8];
        #pragma unroll
        for (int ks = 0; ks < 8; ++ks)
            bv[ks] = *(const short8*)&bs[((w * 8 + ks) * 64 + lane) * 8];
        f32x4 af[4];
        #pragma unroll
        for (int tile = 0; tile < 4; ++tile) af[tile] = (f32x4){0.f, 0.f, 0.f, 0.f};
        #pragma unroll
        for (int ks = 0; ks < 8; ++ks) {
            #pragma unroll
            for (int tile = 0; tile < 4; ++tile)
                af[tile] = __builtin_amdgcn_mfma_f32_16x16x32_bf16(afr[tile][ks], bv[ks], af[tile], 0, 0, 0);
        }

        const int nt   = w * 16 + c;
        const int code = nt * 16 + lr;
        const float cs1 = __fadd_rn(csl[code], 1.0f);   // +1: score>0 (bit order = float order)
        if (cc < NCHUNK) {
            // pass 1: per-row running float min
            #pragma unroll
            for (int tile = 0; tile < 4; ++tile)
                #pragma unroll
                for (int j = 0; j < 4; ++j) {
                    float s = __fmaf_rn(-2.f, af[tile][j], cs1);
                    runp[tile][j] = fminf(runp[tile][j], s);
                }
        } else {
            // pass 2: bit-identical recompute, append candidates
            #pragma unroll
            for (int tile = 0; tile < 4; ++tile)
                #pragma unroll
                for (int j = 0; j < 4; ++j) {
                    float s = __fmaf_rn(-2.f, af[tile][j], cs1);
                    if (s <= thr[tile][j]) {
                        int row = tile * 16 + lg * 4 + j;
                        int pos = atomicAdd(&cnt, 1);
                        if (pos < CAP) list[pos] = ((unsigned)row << 10) | (unsigned)code;
                        else ovf = 1;
                    }
                }
        }

        // pass-1 -> pass-2 boundary: butterfly over lr, cross-wave combine via LDS
        if (cc == NCHUNK - 1) {
            #pragma unroll
            for (int tile = 0; tile < 4; ++tile)
                #pragma unroll
                for (int j = 0; j < 4; ++j) {
                    float v = runp[tile][j];
                    v = fminf(v, __shfl_xor(v, 1, 64));
                    v = fminf(v, __shfl_xor(v, 2, 64));
                    v = fminf(v, __shfl_xor(v, 4, 64));
                    v = fminf(v, __shfl_xor(v, 8, 64));
                    runp[tile][j] = v;
                }
            if (lr == 0) {
                #pragma unroll
                for (int tile = 0; tile < 4; ++tile)
                    #pragma unroll
                    for (int j = 0; j < 4; ++j)
                        wred[w][tile * 16 + lg * 4 + j] = runp[tile][j];
            }
        }
        __syncthreads();   // staged chunk cc+1 visible; buf[cc&1] readers done
        if (cc == NCHUNK - 1) {
            if (t < RPB) {
                float m = fminf(fminf(wred[0][t], wred[1][t]), fminf(wred[2][t], wred[3][t]));
                thrl[t] = m + MARGIN;
            }
            __syncthreads();
            #pragma unroll
            for (int tile = 0; tile < 4; ++tile)
                #pragma unroll
                for (int j = 0; j < 4; ++j) thr[tile][j] = thrl[tile * 16 + lg * 4 + j];
        }
    }

    // ---- exact rescore (r2-proven chain + grid formula), u64 first-index argmin ----
    if (ovf || cnt > CAP) {
        for (int it = t; it < RPB * KCODES; it += 256) {   // safety net (never fires)
            int row = it >> 10, code = it & (KCODES - 1);
            float dot = exact_dot(x + (size_t)(r0 + row) * DDIM, cb + (size_t)code * DDIM);
            float s   = __fmaf_rn(-2.f, dot, __fadd_rn(csl[code], xsqr[r0 + row]));
            atomicMin(&keys[row], ((unsigned long long)__float_as_uint(s) << 32) | (unsigned)code);
        }
    } else {
        for (int i = t; i < cnt; i += 256) {
            unsigned e = list[i];
            int row = (int)(e >> 10), code = (int)(e & 0x3FFu);
            float dot = exact_dot(x + (size_t)(r0 + row) * DDIM, cb + (size_t)code * DDIM);
            float s   = __fmaf_rn(-2.f, dot, __fadd_rn(csl[code], xsqr[r0 + row]));
            atomicMin(&keys[row], ((unsigned long long)__float_as_uint(s) << 32) | (unsigned)code);
        }
    }
    __syncthreads();

    if (t < RPB) {
        int code = (int)(unsigned)(keys[t] & 0xffffffffu);
        fidx[t] = code;
        out[(size_t)2 * NROWS * DDIM + (r0 + t)] = (float)code;
    }
    __syncthreads();

    // gather winning codes: 64 rows x 64 float4, coalesced
    const float4* cb4  = (const float4*)cb;
    float4*       out0 = (float4*)out;
    float4*       out1 = out0 + (size_t)NROWS * (DDIM / 4);
    #pragma unroll
    for (int i = 0; i < 16; ++i) {
        int it  = i * 256 + t;
        int row = it >> 6, col = it & 63;
        float4 v = cb4[(size_t)fidx[row] * (DDIM / 4) + col];
        size_t o = (size_t)(r0 + row) * (DDIM / 4) + col;
        out0[o] = v;
        out1[o] = v;
    }
}

extern "C" void kernel_launch(void* const* d_in, const int* in_sizes, int n_in,
                              void* d_out, int out_size, void* d_ws, size_t ws_size,
                              hipStream_t stream) {
    const float* x   = (const float*)d_in[0];   // z_e_x   [32768,256]
    const float* cb  = (const float*)d_in[1];   // codebook [1024,256]
    float*       out = (float*)d_out;

    float* ws_csqr = (float*)d_ws;                // [1024]
    float* ws_xsqr = ws_csqr + KCODES;            // [32768]
    short* ws_cbh  = (short*)(ws_xsqr + NROWS);   // [1024*256] bf16 frags

    vq_cbfrag<<<128,        256, 0, stream>>>(cb, ws_cbh);
    vq_csqr  <<<256,        256, 0, stream>>>(cb, ws_csqr);
    vq_xsqr  <<<NROWS / 4,  256, 0, stream>>>(x, ws_xsqr);
    vq_main  <<<NROWS / RPB, 256, 0, stream>>>(x, cb, ws_cbh, ws_csqr, ws_xsqr, out);
}